// Round 1
// baseline (651.096 us; speedup 1.0000x reference)
//
#include <hip/hip_runtime.h>
#include <cstdint>

#define B_N 32
#define C_N 192
#define W_N 56
#define HW_N 3136
#define CO_N 384
#define K_N 384
#define M_N 100352   // B_N * HW_N

typedef unsigned short u16;
typedef unsigned int u32;
typedef __attribute__((ext_vector_type(8))) short short8;
typedef __attribute__((ext_vector_type(4))) float floatx4;

__device__ __forceinline__ u16 bf16rne(float f) {
  union { float f; u32 u; } v; v.f = f;
  u32 r = (v.u + 0x7FFFu + ((v.u >> 16) & 1u)) >> 16;
  return (u16)r;
}

// ---- direct global->LDS staging (16B/lane). lbase must be wave-uniform. ----
__device__ __forceinline__ void stage16(const void* g, void* lbase, int lane) {
#if __has_builtin(__builtin_amdgcn_global_load_lds)
  __builtin_amdgcn_global_load_lds(
      (const __attribute__((address_space(1))) void*)(uintptr_t)g,
      (__attribute__((address_space(3))) void*)(u32)(uintptr_t)lbase,
      16, 0, 0);
#else
  *(uint4*)((char*)lbase + lane * 16) = *(const uint4*)g;
#endif
}

// ============ K0: fold BN consts, convert W to bf16 ============
__global__ __launch_bounds__(256) void prep_consts(
    const float* __restrict__ Wc, const float* __restrict__ bconv,
    const float* __restrict__ gamma, const float* __restrict__ beta,
    const float* __restrict__ rmean, const float* __restrict__ rvar,
    u16* __restrict__ Wbf, float* __restrict__ alphaV, float* __restrict__ betaV) {
  int idx = blockIdx.x * 256 + threadIdx.x;
  if (idx < CO_N * K_N) Wbf[idx] = bf16rne(Wc[idx]);
  if (idx < CO_N) {
    float s = gamma[idx] * rsqrtf(rvar[idx] + 1e-5f);
    alphaV[idx] = s;
    betaV[idx] = bconv[idx] * s + beta[idx] - rmean[idx] * s;
  }
}

// ============ K1: per-(b,c) plane -> xj (bf16) ============
// xj[h,w] = relu(x[h,w] - min( min_{h''==h mod2, h''!=h} x[h'',w],
//                              min_{w''==w mod2, w''!=w} x[h,w''] ))
__global__ __launch_bounds__(256) void xj_compute(const float* __restrict__ x,
                                                  u16* __restrict__ XJ) {
  __shared__ float pl[HW_N];
  __shared__ float rmin1[112], rmin2[112], cmin1[112], cmin2[112];
  __shared__ int rarg[112], carg[112];
  int tid = threadIdx.x;
  size_t base = (size_t)blockIdx.x * HW_N;
  const float4* xp4 = (const float4*)(x + base);
  #pragma unroll 1
  for (int i = tid; i < HW_N / 4; i += 256) ((float4*)pl)[i] = xp4[i];
  __syncthreads();
  if (tid < 112) {            // row-direction structure: per (w, parity)
    int ww = tid >> 1, p = tid & 1;
    float m1 = 3e38f, m2 = 3e38f; int am = -1;
    #pragma unroll
    for (int j = 0; j < 28; ++j) {
      int h = p + 2 * j;
      float v = pl[h * W_N + ww];
      if (v < m1) { m2 = m1; m1 = v; am = h; } else if (v < m2) m2 = v;
    }
    rmin1[tid] = m1; rmin2[tid] = m2; rarg[tid] = am;
  } else if (tid < 224) {     // col-direction structure: per (h, parity)
    int t = tid - 112;
    int hh = t >> 1, p = t & 1;
    float m1 = 3e38f, m2 = 3e38f; int am = -1;
    #pragma unroll
    for (int j = 0; j < 28; ++j) {
      int wv = p + 2 * j;
      float v = pl[hh * W_N + wv];
      if (v < m1) { m2 = m1; m1 = v; am = wv; } else if (v < m2) m2 = v;
    }
    cmin1[t] = m1; cmin2[t] = m2; carg[t] = am;
  }
  __syncthreads();
  u16* op = XJ + base;
  #pragma unroll 1
  for (int i4 = tid; i4 < HW_N / 4; i4 += 256) {
    int idx = i4 * 4;
    int h = idx / W_N;
    int w0 = idx - h * W_N;   // rows are multiples of 4 wide -> same h for all 4
    ushort4 r;
    u16* rp = &r.x;
    #pragma unroll
    for (int j = 0; j < 4; ++j) {
      int wv = w0 + j;
      float v = pl[idx + j];
      int rt = (wv << 1) | (h & 1);
      float rm = (rarg[rt] == h) ? rmin2[rt] : rmin1[rt];
      int ct = (h << 1) | (wv & 1);
      float cm = (carg[ct] == wv) ? cmin2[ct] : cmin1[ct];
      float xj = v - fminf(rm, cm);
      rp[j] = bf16rne(fmaxf(xj, 0.0f));
    }
    *(ushort4*)(op + idx) = r;
  }
}

// ============ K2: pack XC[M][384] bf16 (LDS transpose) ============
#define S1 392          // row stride (ushorts): 16B-aligned rows, 2-way-free bank pattern
__global__ __launch_bounds__(256) void pack_xc(const float* __restrict__ x,
                                               const u16* __restrict__ XJ,
                                               u16* __restrict__ XC) {
  __shared__ __align__(16) u16 tile[64 * S1];   // 50176 B
  u32* tile32 = (u32*)tile;
  int tid = threadIdx.x;
  int m0 = blockIdx.x << 6;       // 64 pixels per block; 3136 % 64 == 0, no b-crossing
  int b = m0 / HW_N;
  int p0 = m0 - b * HW_N;
  int kp15 = tid & 15;
  int pg = tid >> 4;              // 0..15
  int px = pg << 2;
  const float* xb = x + (size_t)b * C_N * HW_N + p0 + px;
  const u16* jb = XJ + (size_t)b * C_N * HW_N + p0 + px;
  #pragma unroll
  for (int i = 0; i < 6; ++i) {   // x half: channels 0..191, paired
    int kp = i * 16 + kp15;
    int k = kp * 2;
    float4 v0 = *(const float4*)(xb + (size_t)k * HW_N);
    float4 v1 = *(const float4*)(xb + (size_t)(k + 1) * HW_N);
    const float* a0 = &v0.x; const float* a1 = &v1.x;
    #pragma unroll
    for (int j = 0; j < 4; ++j) {
      u32 d = (u32)bf16rne(a0[j]) | ((u32)bf16rne(a1[j]) << 16);
      tile32[(px + j) * (S1 / 2) + kp] = d;
    }
  }
  #pragma unroll
  for (int i = 0; i < 6; ++i) {   // xj half: channels 192..383
    int kp = i * 16 + kp15;
    int k = kp * 2;
    ushort4 v0 = *(const ushort4*)(jb + (size_t)k * HW_N);
    ushort4 v1 = *(const ushort4*)(jb + (size_t)(k + 1) * HW_N);
    const u16* a0 = &v0.x; const u16* a1 = &v1.x;
    #pragma unroll
    for (int j = 0; j < 4; ++j) {
      u32 d = (u32)a0[j] | ((u32)a1[j] << 16);
      tile32[(px + j) * (S1 / 2) + 96 + kp] = d;
    }
  }
  __syncthreads();
  u16* ob = XC + (size_t)m0 * K_N;
  #pragma unroll
  for (int i = 0; i < 12; ++i) {  // fully coalesced store: addr == m0*384 + task*8
    int task = tid + i * 256;
    int p = task / 48;
    int kc = task - p * 48;
    uint4 v = *(const uint4*)(tile32 + p * (S1 / 2) + kc * 4);
    *(uint4*)(ob + (size_t)task * 8) = v;
  }
}

// ============ K3: GEMM (XC[M,384] x Wbf[384,384]^T) + BN + GELU ============
__global__ __launch_bounds__(256) void gemm_bn_gelu(
    const u16* __restrict__ XC, const u16* __restrict__ Wbf,
    const float* __restrict__ alphaV, const float* __restrict__ betaV,
    float* __restrict__ out) {
  __shared__ __align__(16) u16 smem[8192];   // As[128][32] + Bs[128][32]
  u16* As = smem;
  u16* Bs = smem + 4096;
  int tid = threadIdx.x;
  int lane = tid & 63;
  int w = tid >> 6;
  int bid = blockIdx.x;
  int bn = bid % 3;           // 3 n-tiles grouped adjacent for A-tile L2 reuse
  int bm = bid / 3;
  int m0 = bm << 7, n0 = bn << 7;
  int wm = w & 1, wn = w >> 1;
  int l15 = lane & 15, quad = lane >> 4;

  const u16* gA = XC + (size_t)(m0 + w * 32 + (lane >> 2)) * K_N + (lane & 3) * 8;
  const u16* gB = Wbf + (size_t)(n0 + w * 32 + (lane >> 2)) * K_N + (lane & 3) * 8;
  u16* lA = As + (w * 32) * 32;
  u16* lB = Bs + (w * 32) * 32;

  floatx4 acc[4][4];
  #pragma unroll
  for (int i = 0; i < 4; ++i)
    #pragma unroll
    for (int j = 0; j < 4; ++j) acc[i][j] = (floatx4)0.0f;

  #pragma unroll 1
  for (int ki = 0; ki < 12; ++ki) {
    int k0 = ki * 32;
    __syncthreads();
    stage16(gA + k0, lA, lane);
    stage16(gA + 16 * K_N + k0, lA + 16 * 32, lane);
    stage16(gB + k0, lB, lane);
    stage16(gB + 16 * K_N + k0, lB + 16 * 32, lane);
    __syncthreads();
    short8 aF[4], bF[4];
    #pragma unroll
    for (int mi = 0; mi < 4; ++mi)
      aF[mi] = *(const short8*)(As + (wm * 64 + mi * 16 + l15) * 32 + quad * 8);
    #pragma unroll
    for (int ni = 0; ni < 4; ++ni)
      bF[ni] = *(const short8*)(Bs + (wn * 64 + ni * 16 + l15) * 32 + quad * 8);
    #pragma unroll
    for (int mi = 0; mi < 4; ++mi)
      #pragma unroll
      for (int ni = 0; ni < 4; ++ni)
        acc[mi][ni] = __builtin_amdgcn_mfma_f32_16x16x32_bf16(aF[mi], bF[ni], acc[mi][ni], 0, 0, 0);
  }

  // epilogue: BN affine + exact GELU, LDS transpose, coalesced [o][p] stores
  float av[4], bv[4];
  #pragma unroll
  for (int ni = 0; ni < 4; ++ni) {
    int o = n0 + wn * 64 + ni * 16 + l15;
    av[ni] = alphaV[o];
    bv[ni] = betaV[o];
  }
  float* ep = (float*)smem;      // 128 rows (o) x stride 20 floats (m-slice of 16)
  #pragma unroll 1
  for (int s = 0; s < 8; ++s) {  // 8 m-slices of 16; 3136 % 16 == 0, slice never crosses b
    __syncthreads();
    if (wm == (s >> 2)) {
      int mi = s & 3;
      #pragma unroll
      for (int ni = 0; ni < 4; ++ni) {
        floatx4 a = acc[mi][ni];
        float4 g;
        float* gp = &g.x;
        #pragma unroll
        for (int i = 0; i < 4; ++i) {
          float t = a[i] * av[ni] + bv[ni];
          gp[i] = 0.5f * t * (1.0f + erff(t * 0.70710678118654752f));
        }
        *(float4*)&ep[(wn * 64 + ni * 16 + l15) * 20 + quad * 4] = g;
      }
    }
    __syncthreads();
    int mg = m0 + s * 16;
    int bb = mg / HW_N;
    int pp = mg - bb * HW_N;
    float* ob = out + ((size_t)bb * CO_N + n0) * HW_N + pp;
    #pragma unroll
    for (int t2 = 0; t2 < 2; ++t2) {
      int task = tid + t2 * 256;
      int o = task >> 2, ch = task & 3;
      float4 v = *(float4*)&ep[o * 20 + ch * 4];
      *(float4*)(ob + (size_t)o * HW_N + ch * 4) = v;
    }
  }
}

extern "C" void kernel_launch(void* const* d_in, const int* in_sizes, int n_in,
                              void* d_out, int out_size, void* d_ws, size_t ws_size,
                              hipStream_t stream) {
  const float* x  = (const float*)d_in[0];
  const float* Wc = (const float*)d_in[1];
  const float* bc = (const float*)d_in[2];
  const float* gm = (const float*)d_in[3];
  const float* bt = (const float*)d_in[4];
  const float* rm = (const float*)d_in[5];
  const float* rv = (const float*)d_in[6];
  float* out = (float*)d_out;

  char* ws = (char*)d_ws;
  size_t offXC = 0;
  size_t offXJ = offXC + (size_t)M_N * K_N * 2;                  // 77,070,336
  size_t offWb = offXJ + (size_t)B_N * C_N * HW_N * 2;           // +38,535,168
  size_t offAl = offWb + (size_t)CO_N * K_N * 2;                 // +294,912
  u16* XC = (u16*)(ws + offXC);
  u16* XJ = (u16*)(ws + offXJ);
  u16* Wbf = (u16*)(ws + offWb);
  float* alphaV = (float*)(ws + offAl);
  float* betaV = alphaV + CO_N;

  hipLaunchKernelGGL(prep_consts, dim3(576), dim3(256), 0, stream,
                     Wc, bc, gm, bt, rm, rv, Wbf, alphaV, betaV);
  hipLaunchKernelGGL(xj_compute, dim3(B_N * C_N), dim3(256), 0, stream, x, XJ);
  hipLaunchKernelGGL(pack_xc, dim3(M_N / 64), dim3(256), 0, stream, x, XJ, XC);
  hipLaunchKernelGGL(gemm_bn_gelu, dim3(784 * 3), dim3(256), 0, stream,
                     XC, Wbf, alphaV, betaV, out);
}

// Round 2
// 618.908 us; speedup vs baseline: 1.0520x; 1.0520x over previous
//
#include <hip/hip_runtime.h>
#include <cstdint>

#define B_N 32
#define C_N 192
#define W_N 56
#define HW_N 3136
#define CO_N 384
#define K_N 384
#define M_N 100352   // B_N * HW_N

typedef unsigned short u16;
typedef unsigned int u32;
typedef __attribute__((ext_vector_type(8))) short short8;
typedef __attribute__((ext_vector_type(4))) float floatx4;

__device__ __forceinline__ u16 bf16rne(float f) {
  union { float f; u32 u; } v; v.f = f;
  u32 r = (v.u + 0x7FFFu + ((v.u >> 16) & 1u)) >> 16;
  return (u16)r;
}

// ---- direct global->LDS staging (16B/lane). lbase must be wave-uniform. ----
__device__ __forceinline__ void stage16(const void* g, void* lbase, int lane) {
#if __has_builtin(__builtin_amdgcn_global_load_lds)
  __builtin_amdgcn_global_load_lds(
      (const __attribute__((address_space(1))) void*)(uintptr_t)g,
      (__attribute__((address_space(3))) void*)(u32)(uintptr_t)lbase,
      16, 0, 0);
#else
  *(uint4*)((char*)lbase + lane * 16) = *(const uint4*)g;
#endif
}

// ============ K0: fold BN consts, convert W to bf16 ============
__global__ __launch_bounds__(256) void prep_consts(
    const float* __restrict__ Wc, const float* __restrict__ bconv,
    const float* __restrict__ gamma, const float* __restrict__ beta,
    const float* __restrict__ rmean, const float* __restrict__ rvar,
    u16* __restrict__ Wbf, float* __restrict__ alphaV, float* __restrict__ betaV) {
  int idx = blockIdx.x * 256 + threadIdx.x;
  if (idx < CO_N * K_N) Wbf[idx] = bf16rne(Wc[idx]);
  if (idx < CO_N) {
    float s = gamma[idx] * rsqrtf(rvar[idx] + 1e-5f);
    alphaV[idx] = s;
    betaV[idx] = bconv[idx] * s + beta[idx] - rmean[idx] * s;
  }
}

// ============ K1: per-(b,c) plane -> xj (bf16) ============
// xj[h,w] = relu(x[h,w] - min( min over same-parity h''!=h of x[h'',w],
//                              min over same-parity w''!=w of x[h,w''] ))
__global__ __launch_bounds__(256) void xj_compute(const float* __restrict__ x,
                                                  u16* __restrict__ XJ) {
  __shared__ float pl[HW_N];
  __shared__ float rmin1[112], rmin2[112], cmin1[112], cmin2[112];
  __shared__ int rarg[112], carg[112];
  int tid = threadIdx.x;
  size_t base = (size_t)blockIdx.x * HW_N;
  const float4* xp4 = (const float4*)(x + base);
  #pragma unroll 1
  for (int i = tid; i < HW_N / 4; i += 256) ((float4*)pl)[i] = xp4[i];
  __syncthreads();
  if (tid < 112) {            // row-direction structure: per (w, parity)
    int ww = tid >> 1, p = tid & 1;
    float m1 = 3e38f, m2 = 3e38f; int am = -1;
    #pragma unroll
    for (int j = 0; j < 28; ++j) {
      int h = p + 2 * j;
      float v = pl[h * W_N + ww];
      if (v < m1) { m2 = m1; m1 = v; am = h; } else if (v < m2) m2 = v;
    }
    rmin1[tid] = m1; rmin2[tid] = m2; rarg[tid] = am;
  } else if (tid < 224) {     // col-direction structure: per (h, parity)
    int t = tid - 112;
    int hh = t >> 1, p = t & 1;
    float m1 = 3e38f, m2 = 3e38f; int am = -1;
    #pragma unroll
    for (int j = 0; j < 28; ++j) {
      int wv = p + 2 * j;
      float v = pl[hh * W_N + wv];
      if (v < m1) { m2 = m1; m1 = v; am = wv; } else if (v < m2) m2 = v;
    }
    cmin1[t] = m1; cmin2[t] = m2; carg[t] = am;
  }
  __syncthreads();
  u16* op = XJ + base;
  #pragma unroll 1
  for (int i4 = tid; i4 < HW_N / 4; i4 += 256) {
    int idx = i4 * 4;
    int h = idx / W_N;
    int w0 = idx - h * W_N;   // rows are multiples of 4 wide -> same h for all 4
    ushort4 r;
    u16* rp = &r.x;
    #pragma unroll
    for (int j = 0; j < 4; ++j) {
      int wv = w0 + j;
      float v = pl[idx + j];
      int rt = (wv << 1) | (h & 1);
      float rm = (rarg[rt] == h) ? rmin2[rt] : rmin1[rt];
      int ct = (h << 1) | (wv & 1);
      float cm = (carg[ct] == wv) ? cmin2[ct] : cmin1[ct];
      float xj = v - fminf(rm, cm);
      rp[j] = bf16rne(fmaxf(xj, 0.0f));
    }
    *(ushort4*)(op + idx) = r;
  }
}

// ============ K2: pack XC[M][384] bf16 (LDS transpose) ============
#define S1 392          // row stride (ushorts): 16B-aligned rows
__global__ __launch_bounds__(256) void pack_xc(const float* __restrict__ x,
                                               const u16* __restrict__ XJ,
                                               u16* __restrict__ XC) {
  __shared__ __align__(16) u16 tile[64 * S1];   // 50176 B
  u32* tile32 = (u32*)tile;
  int tid = threadIdx.x;
  int m0 = blockIdx.x << 6;       // 64 pixels per block; 3136 % 64 == 0, no b-crossing
  int b = m0 / HW_N;
  int p0 = m0 - b * HW_N;
  int kp15 = tid & 15;
  int pg = tid >> 4;              // 0..15
  int px = pg << 2;
  const float* xb = x + (size_t)b * C_N * HW_N + p0 + px;
  const u16* jb = XJ + (size_t)b * C_N * HW_N + p0 + px;
  #pragma unroll
  for (int i = 0; i < 6; ++i) {   // x half: channels 0..191, paired
    int kp = i * 16 + kp15;
    int k = kp * 2;
    float4 v0 = *(const float4*)(xb + (size_t)k * HW_N);
    float4 v1 = *(const float4*)(xb + (size_t)(k + 1) * HW_N);
    const float* a0 = &v0.x; const float* a1 = &v1.x;
    #pragma unroll
    for (int j = 0; j < 4; ++j) {
      u32 d = (u32)bf16rne(a0[j]) | ((u32)bf16rne(a1[j]) << 16);
      tile32[(px + j) * (S1 / 2) + kp] = d;
    }
  }
  #pragma unroll
  for (int i = 0; i < 6; ++i) {   // xj half: channels 192..383
    int kp = i * 16 + kp15;
    int k = kp * 2;
    ushort4 v0 = *(const ushort4*)(jb + (size_t)k * HW_N);
    ushort4 v1 = *(const ushort4*)(jb + (size_t)(k + 1) * HW_N);
    const u16* a0 = &v0.x; const u16* a1 = &v1.x;
    #pragma unroll
    for (int j = 0; j < 4; ++j) {
      u32 d = (u32)a0[j] | ((u32)a1[j] << 16);
      tile32[(px + j) * (S1 / 2) + 96 + kp] = d;
    }
  }
  __syncthreads();
  u16* ob = XC + (size_t)m0 * K_N;
  #pragma unroll
  for (int i = 0; i < 12; ++i) {  // fully coalesced store: addr == m0*384 + task*8
    int task = tid + i * 256;
    int p = task / 48;
    int kc = task - p * 48;
    uint4 v = *(const uint4*)(tile32 + p * (S1 / 2) + kc * 4);
    *(uint4*)(ob + (size_t)task * 8) = v;
  }
}

// ============ K3: GEMM (XC[M,384] x Wbf[384,384]^T) + BN + GELU ============
// LDS k-chunk XOR swizzle: element (row, logical 16B chunk q) lives at slot
// q ^ ((row>>1)&3). Staging stays lane-contiguous (only global addr permuted);
// frag ds_read_b128 drops from 8-way to 2-way (free) bank aliasing.
__global__ __launch_bounds__(256) void gemm_bn_gelu(
    const u16* __restrict__ XC, const u16* __restrict__ Wbf,
    const float* __restrict__ alphaV, const float* __restrict__ betaV,
    float* __restrict__ out) {
  __shared__ __align__(16) char smem_raw[16896]; // GEMM: 16384 B; epilogue: 32x132 floats
  u16* As = (u16*)smem_raw;
  u16* Bs = As + 4096;
  float* ep = (float*)smem_raw;
  int tid = threadIdx.x;
  int lane = tid & 63;
  int w = tid >> 6;
  // XCD swizzle: the 3 n-blocks sharing one A-tile all land on XCD (bid%8)
  int bid = blockIdx.x;
  int xcd = bid & 7;
  int slot = bid >> 3;        // 0..293
  int bn = slot % 3;
  int bmg = slot / 3;         // 0..97
  int bm = bmg * 8 + xcd;     // 0..783
  int m0 = bm << 7, n0 = bn << 7;
  int wm = w & 1, wn = w >> 1;
  int l15 = lane & 15, quad = lane >> 4;

  int ksw = ((lane & 3) ^ ((lane >> 3) & 3)) * 8;   // staging-side chunk permute
  const u16* gA = XC + (size_t)(m0 + w * 32 + (lane >> 2)) * K_N + ksw;
  const u16* gB = Wbf + (size_t)(n0 + w * 32 + (lane >> 2)) * K_N + ksw;
  u16* lA = As + (w * 32) * 32;
  u16* lB = Bs + (w * 32) * 32;

  floatx4 acc[4][4];
  #pragma unroll
  for (int i = 0; i < 4; ++i)
    #pragma unroll
    for (int j = 0; j < 4; ++j) acc[i][j] = (floatx4)0.0f;

  int rsw = (quad ^ ((l15 >> 1) & 3)) * 8;          // read-side chunk slot
  #pragma unroll 1
  for (int ki = 0; ki < 12; ++ki) {
    int k0 = ki * 32;
    __syncthreads();
    stage16(gA + k0, lA, lane);
    stage16(gA + 16 * K_N + k0, lA + 16 * 32, lane);
    stage16(gB + k0, lB, lane);
    stage16(gB + 16 * K_N + k0, lB + 16 * 32, lane);
    __syncthreads();
    short8 aF[4], bF[4];
    #pragma unroll
    for (int mi = 0; mi < 4; ++mi)
      aF[mi] = *(const short8*)(As + (wm * 64 + mi * 16 + l15) * 32 + rsw);
    #pragma unroll
    for (int ni = 0; ni < 4; ++ni)
      bF[ni] = *(const short8*)(Bs + (wn * 64 + ni * 16 + l15) * 32 + rsw);
    #pragma unroll
    for (int mi = 0; mi < 4; ++mi)
      #pragma unroll
      for (int ni = 0; ni < 4; ++ni)
        acc[mi][ni] = __builtin_amdgcn_mfma_f32_16x16x32_bf16(aF[mi], bF[ni], acc[mi][ni], 0, 0, 0);
  }

  // epilogue: BN affine + exact GELU; 4 chunks of 32 o-rows; each out row gets
  // one contiguous 512 B store stream (full cache lines, written once).
  float av[4], bv[4];
  #pragma unroll
  for (int ni = 0; ni < 4; ++ni) {
    int o = n0 + wn * 64 + ni * 16 + l15;
    av[ni] = alphaV[o];
    bv[ni] = betaV[o];
  }
  #pragma unroll 1
  for (int oc = 0; oc < 4; ++oc) {   // o-chunk = [n0+oc*32, n0+oc*32+32)
    __syncthreads();
    if (wn == (oc >> 1)) {
      int nbase = (oc & 1) * 2;
      #pragma unroll
      for (int ni2 = 0; ni2 < 2; ++ni2) {
        int ni = nbase + ni2;
        #pragma unroll
        for (int mi = 0; mi < 4; ++mi) {
          floatx4 a = acc[mi][ni];
          float4 g;
          float* gp = &g.x;
          #pragma unroll
          for (int i = 0; i < 4; ++i) {
            float t = a[i] * av[ni] + bv[ni];
            gp[i] = 0.5f * t * (1.0f + erff(t * 0.70710678118654752f));
          }
          // chunk-row r = ni2*16+l15 (o = n0+oc*32+r), col = m within tile
          *(float4*)&ep[(ni2 * 16 + l15) * 132 + wm * 64 + mi * 16 + quad * 4] = g;
        }
      }
    }
    __syncthreads();
    #pragma unroll
    for (int it = 0; it < 4; ++it) {
      int task = tid + it * 256;     // 0..1023
      int r = task >> 5;             // 0..31
      int c4 = task & 31;            // float4 index along m
      float4 v = *(float4*)&ep[r * 132 + c4 * 4];
      int gm = m0 + c4 * 4;          // tile may cross batch at 64-m boundary
      int bb = gm / HW_N;
      int pp = gm - bb * HW_N;
      *(float4*)(out + ((size_t)(bb * CO_N + n0 + oc * 32 + r)) * HW_N + pp) = v;
    }
  }
}

extern "C" void kernel_launch(void* const* d_in, const int* in_sizes, int n_in,
                              void* d_out, int out_size, void* d_ws, size_t ws_size,
                              hipStream_t stream) {
  const float* x  = (const float*)d_in[0];
  const float* Wc = (const float*)d_in[1];
  const float* bc = (const float*)d_in[2];
  const float* gm = (const float*)d_in[3];
  const float* bt = (const float*)d_in[4];
  const float* rm = (const float*)d_in[5];
  const float* rv = (const float*)d_in[6];
  float* out = (float*)d_out;

  char* ws = (char*)d_ws;
  size_t offXC = 0;
  size_t offXJ = offXC + (size_t)M_N * K_N * 2;                  // 77,070,336
  size_t offWb = offXJ + (size_t)B_N * C_N * HW_N * 2;           // +38,535,168
  size_t offAl = offWb + (size_t)CO_N * K_N * 2;                 // +294,912
  u16* XC = (u16*)(ws + offXC);
  u16* XJ = (u16*)(ws + offXJ);
  u16* Wbf = (u16*)(ws + offWb);
  float* alphaV = (float*)(ws + offAl);
  float* betaV = alphaV + CO_N;

  hipLaunchKernelGGL(prep_consts, dim3(576), dim3(256), 0, stream,
                     Wc, bc, gm, bt, rm, rv, Wbf, alphaV, betaV);
  hipLaunchKernelGGL(xj_compute, dim3(B_N * C_N), dim3(256), 0, stream, x, XJ);
  hipLaunchKernelGGL(pack_xc, dim3(M_N / 64), dim3(256), 0, stream, x, XJ, XC);
  hipLaunchKernelGGL(gemm_bn_gelu, dim3(784 * 3), dim3(256), 0, stream,
                     XC, Wbf, alphaV, betaV, out);
}

// Round 3
// 530.328 us; speedup vs baseline: 1.2277x; 1.1670x over previous
//
#include <hip/hip_runtime.h>
#include <cstdint>

#define B_N 32
#define C_N 192
#define W_N 56
#define HW_N 3136
#define CO_N 384
#define K_N 384
#define M_N 100352   // B_N * HW_N

typedef unsigned short u16;
typedef unsigned int u32;
typedef __attribute__((ext_vector_type(8))) short short8;
typedef __attribute__((ext_vector_type(4))) float floatx4;

__device__ __forceinline__ u16 bf16rne(float f) {
  union { float f; u32 u; } v; v.f = f;
  u32 r = (v.u + 0x7FFFu + ((v.u >> 16) & 1u)) >> 16;
  return (u16)r;
}

// ---- direct global->LDS staging (16B/lane). lbase must be wave-uniform. ----
__device__ __forceinline__ void stage16(const void* g, void* lbase, int lane) {
#if __has_builtin(__builtin_amdgcn_global_load_lds)
  __builtin_amdgcn_global_load_lds(
      (const __attribute__((address_space(1))) void*)(uintptr_t)g,
      (__attribute__((address_space(3))) void*)(u32)(uintptr_t)lbase,
      16, 0, 0);
#else
  *(uint4*)((char*)lbase + lane * 16) = *(const uint4*)g;
#endif
}

// ============ K0: fold BN consts, convert W to bf16 ============
__global__ __launch_bounds__(256) void prep_consts(
    const float* __restrict__ Wc, const float* __restrict__ bconv,
    const float* __restrict__ gamma, const float* __restrict__ beta,
    const float* __restrict__ rmean, const float* __restrict__ rvar,
    u16* __restrict__ Wbf, float* __restrict__ alphaV, float* __restrict__ betaV) {
  int idx = blockIdx.x * 256 + threadIdx.x;
  if (idx < CO_N * K_N) Wbf[idx] = bf16rne(Wc[idx]);
  if (idx < CO_N) {
    float s = gamma[idx] * rsqrtf(rvar[idx] + 1e-5f);
    alphaV[idx] = s;
    betaV[idx] = bconv[idx] * s + beta[idx] - rmean[idx] * s;
  }
}

// ============ K1: per-(b,c) plane -> xj (bf16) ============
__global__ __launch_bounds__(256) void xj_compute(const float* __restrict__ x,
                                                  u16* __restrict__ XJ) {
  __shared__ float pl[HW_N];
  __shared__ float rmin1[112], rmin2[112], cmin1[112], cmin2[112];
  __shared__ int rarg[112], carg[112];
  int tid = threadIdx.x;
  size_t base = (size_t)blockIdx.x * HW_N;
  const float4* xp4 = (const float4*)(x + base);
  #pragma unroll 1
  for (int i = tid; i < HW_N / 4; i += 256) ((float4*)pl)[i] = xp4[i];
  __syncthreads();
  if (tid < 112) {            // row-direction structure: per (w, parity)
    int ww = tid >> 1, p = tid & 1;
    float m1 = 3e38f, m2 = 3e38f; int am = -1;
    #pragma unroll
    for (int j = 0; j < 28; ++j) {
      int h = p + 2 * j;
      float v = pl[h * W_N + ww];
      if (v < m1) { m2 = m1; m1 = v; am = h; } else if (v < m2) m2 = v;
    }
    rmin1[tid] = m1; rmin2[tid] = m2; rarg[tid] = am;
  } else if (tid < 224) {     // col-direction structure: per (h, parity)
    int t = tid - 112;
    int hh = t >> 1, p = t & 1;
    float m1 = 3e38f, m2 = 3e38f; int am = -1;
    #pragma unroll
    for (int j = 0; j < 28; ++j) {
      int wv = p + 2 * j;
      float v = pl[hh * W_N + wv];
      if (v < m1) { m2 = m1; m1 = v; am = wv; } else if (v < m2) m2 = v;
    }
    cmin1[t] = m1; cmin2[t] = m2; carg[t] = am;
  }
  __syncthreads();
  u16* op = XJ + base;
  #pragma unroll 1
  for (int i4 = tid; i4 < HW_N / 4; i4 += 256) {
    int idx = i4 * 4;
    int h = idx / W_N;
    int w0 = idx - h * W_N;
    ushort4 r;
    u16* rp = &r.x;
    #pragma unroll
    for (int j = 0; j < 4; ++j) {
      int wv = w0 + j;
      float v = pl[idx + j];
      int rt = (wv << 1) | (h & 1);
      float rm = (rarg[rt] == h) ? rmin2[rt] : rmin1[rt];
      int ct = (h << 1) | (wv & 1);
      float cm = (carg[ct] == wv) ? cmin2[ct] : cmin1[ct];
      float xj = v - fminf(rm, cm);
      rp[j] = bf16rne(fmaxf(xj, 0.0f));
    }
    *(ushort4*)(op + idx) = r;
  }
}

// ============ K2: pack XC[M][384] bf16 (LDS transpose) ============
#define S1 392
__global__ __launch_bounds__(256) void pack_xc(const float* __restrict__ x,
                                               const u16* __restrict__ XJ,
                                               u16* __restrict__ XC) {
  __shared__ __align__(16) u16 tile[64 * S1];
  u32* tile32 = (u32*)tile;
  int tid = threadIdx.x;
  int m0 = blockIdx.x << 6;
  int b = m0 / HW_N;
  int p0 = m0 - b * HW_N;
  int kp15 = tid & 15;
  int pg = tid >> 4;
  int px = pg << 2;
  const float* xb = x + (size_t)b * C_N * HW_N + p0 + px;
  const u16* jb = XJ + (size_t)b * C_N * HW_N + p0 + px;
  #pragma unroll
  for (int i = 0; i < 6; ++i) {
    int kp = i * 16 + kp15;
    int k = kp * 2;
    float4 v0 = *(const float4*)(xb + (size_t)k * HW_N);
    float4 v1 = *(const float4*)(xb + (size_t)(k + 1) * HW_N);
    const float* a0 = &v0.x; const float* a1 = &v1.x;
    #pragma unroll
    for (int j = 0; j < 4; ++j) {
      u32 d = (u32)bf16rne(a0[j]) | ((u32)bf16rne(a1[j]) << 16);
      tile32[(px + j) * (S1 / 2) + kp] = d;
    }
  }
  #pragma unroll
  for (int i = 0; i < 6; ++i) {
    int kp = i * 16 + kp15;
    int k = kp * 2;
    ushort4 v0 = *(const ushort4*)(jb + (size_t)k * HW_N);
    ushort4 v1 = *(const ushort4*)(jb + (size_t)(k + 1) * HW_N);
    const u16* a0 = &v0.x; const u16* a1 = &v1.x;
    #pragma unroll
    for (int j = 0; j < 4; ++j) {
      u32 d = (u32)a0[j] | ((u32)a1[j] << 16);
      tile32[(px + j) * (S1 / 2) + 96 + kp] = d;
    }
  }
  __syncthreads();
  u16* ob = XC + (size_t)m0 * K_N;
  #pragma unroll
  for (int i = 0; i < 12; ++i) {
    int task = tid + i * 256;
    int p = task / 48;
    int kc = task - p * 48;
    uint4 v = *(const uint4*)(tile32 + p * (S1 / 2) + kc * 4);
    *(uint4*)(ob + (size_t)task * 8) = v;
  }
}

// ============ K3: GEMM (XC[M,384] x Wbf[384,384]^T) + BN + GELU ============
// BK=64: 8 stage16 loads in flight per wave per barrier window (2x R2's 4),
// 6 barrier drains instead of 12 -> larger share of the contended HBM bus.
// LDS rows are 64 u16 (128 B). Swizzle: 16B chunk q of row r lives at slot
// q ^ (r & 7). Read side: frag rows l15 0..15 -> slots cover all 8 positions
// -> 32 banks -> 2-way (free). Global side: each 8-lane group covers one
// contiguous 128 B window (chunk-permuted within) -> still fully coalesced.
__global__ __launch_bounds__(256) void gemm_bn_gelu(
    const u16* __restrict__ XC, const u16* __restrict__ Wbf,
    const float* __restrict__ alphaV, const float* __restrict__ betaV,
    float* __restrict__ out) {
  __shared__ __align__(16) char smem_raw[32768]; // As 16K + Bs 16K; epilogue 16896 B
  u16* As = (u16*)smem_raw;
  u16* Bs = As + 8192;
  float* ep = (float*)smem_raw;
  int tid = threadIdx.x;
  int lane = tid & 63;
  int w = tid >> 6;
  // XCD swizzle: 3 n-blocks sharing one A-tile land on the same XCD (bid%8)
  int bid = blockIdx.x;
  int xcd = bid & 7;
  int slot = bid >> 3;
  int bn = slot % 3;
  int bmg = slot / 3;
  int bm = bmg * 8 + xcd;
  int m0 = bm << 7, n0 = bn << 7;
  int wm = w & 1, wn = w >> 1;
  int l15 = lane & 15, quad = lane >> 4;

  // staging address: per call c (8 rows), lane -> row w*32+c*8+(lane>>3),
  // chunk (lane&7)^(row&7)
  int lrow = lane >> 3;               // 0..7 within call
  int lchunkbase = lane & 7;
  floatx4 acc[4][4];
  #pragma unroll
  for (int i = 0; i < 4; ++i)
    #pragma unroll
    for (int j = 0; j < 4; ++j) acc[i][j] = (floatx4)0.0f;

  #pragma unroll 1
  for (int ko = 0; ko < 6; ++ko) {
    int k0 = ko * 64;
    __syncthreads();
    #pragma unroll
    for (int c = 0; c < 4; ++c) {
      int rowbase = w * 32 + c * 8;
      int row = rowbase + lrow;
      int chunk = lchunkbase ^ (row & 7);
      stage16(XC + (size_t)(m0 + row) * K_N + k0 + chunk * 8,
              As + rowbase * 64, lane);
      stage16(Wbf + (size_t)(n0 + row) * K_N + k0 + chunk * 8,
              Bs + rowbase * 64, lane);
    }
    __syncthreads();
    #pragma unroll
    for (int h2 = 0; h2 < 2; ++h2) {
      short8 aF[4], bF[4];
      #pragma unroll
      for (int mi = 0; mi < 4; ++mi) {
        int r = wm * 64 + mi * 16 + l15;
        aF[mi] = *(const short8*)(As + r * 64 + (((h2 * 4 + quad) ^ (r & 7)) * 8));
      }
      #pragma unroll
      for (int ni = 0; ni < 4; ++ni) {
        int r = wn * 64 + ni * 16 + l15;
        bF[ni] = *(const short8*)(Bs + r * 64 + (((h2 * 4 + quad) ^ (r & 7)) * 8));
      }
      #pragma unroll
      for (int mi = 0; mi < 4; ++mi)
        #pragma unroll
        for (int ni = 0; ni < 4; ++ni)
          acc[mi][ni] = __builtin_amdgcn_mfma_f32_16x16x32_bf16(aF[mi], bF[ni], acc[mi][ni], 0, 0, 0);
    }
  }

  // epilogue: BN affine + exact GELU; 4 chunks of 32 o-rows; each out row gets
  // one contiguous 512 B store stream (full cache lines, written once).
  float av[4], bv[4];
  #pragma unroll
  for (int ni = 0; ni < 4; ++ni) {
    int o = n0 + wn * 64 + ni * 16 + l15;
    av[ni] = alphaV[o];
    bv[ni] = betaV[o];
  }
  #pragma unroll 1
  for (int oc = 0; oc < 4; ++oc) {
    __syncthreads();
    if (wn == (oc >> 1)) {
      int nbase = (oc & 1) * 2;
      #pragma unroll
      for (int ni2 = 0; ni2 < 2; ++ni2) {
        int ni = nbase + ni2;
        #pragma unroll
        for (int mi = 0; mi < 4; ++mi) {
          floatx4 a = acc[mi][ni];
          float4 g;
          float* gp = &g.x;
          #pragma unroll
          for (int i = 0; i < 4; ++i) {
            float t = a[i] * av[ni] + bv[ni];
            gp[i] = 0.5f * t * (1.0f + erff(t * 0.70710678118654752f));
          }
          *(float4*)&ep[(ni2 * 16 + l15) * 132 + wm * 64 + mi * 16 + quad * 4] = g;
        }
      }
    }
    __syncthreads();
    #pragma unroll
    for (int it = 0; it < 4; ++it) {
      int task = tid + it * 256;
      int r = task >> 5;
      int c4 = task & 31;
      float4 v = *(float4*)&ep[r * 132 + c4 * 4];
      int gm = m0 + c4 * 4;
      int bb = gm / HW_N;
      int pp = gm - bb * HW_N;
      *(float4*)(out + ((size_t)(bb * CO_N + n0 + oc * 32 + r)) * HW_N + pp) = v;
    }
  }
}

extern "C" void kernel_launch(void* const* d_in, const int* in_sizes, int n_in,
                              void* d_out, int out_size, void* d_ws, size_t ws_size,
                              hipStream_t stream) {
  const float* x  = (const float*)d_in[0];
  const float* Wc = (const float*)d_in[1];
  const float* bc = (const float*)d_in[2];
  const float* gm = (const float*)d_in[3];
  const float* bt = (const float*)d_in[4];
  const float* rm = (const float*)d_in[5];
  const float* rv = (const float*)d_in[6];
  float* out = (float*)d_out;

  char* ws = (char*)d_ws;
  size_t offXC = 0;
  size_t offXJ = offXC + (size_t)M_N * K_N * 2;
  size_t offWb = offXJ + (size_t)B_N * C_N * HW_N * 2;
  size_t offAl = offWb + (size_t)CO_N * K_N * 2;
  u16* XC = (u16*)(ws + offXC);
  u16* XJ = (u16*)(ws + offXJ);
  u16* Wbf = (u16*)(ws + offWb);
  float* alphaV = (float*)(ws + offAl);
  float* betaV = alphaV + CO_N;

  hipLaunchKernelGGL(prep_consts, dim3(576), dim3(256), 0, stream,
                     Wc, bc, gm, bt, rm, rv, Wbf, alphaV, betaV);
  hipLaunchKernelGGL(xj_compute, dim3(B_N * C_N), dim3(256), 0, stream, x, XJ);
  hipLaunchKernelGGL(pack_xc, dim3(M_N / 64), dim3(256), 0, stream, x, XJ, XC);
  hipLaunchKernelGGL(gemm_bn_gelu, dim3(784 * 3), dim3(256), 0, stream,
                     XC, Wbf, alphaV, betaV, out);
}